// Round 9
// baseline (475.911 us; speedup 1.0000x reference)
//
#include <hip/hip_runtime.h>

// LSTM enc(20, in=2) + dec(30, in=h) fused, HID=64, f32 I/O.
// Gates-transposed MFMA recurrence, v_mfma_f32_16x16x32_f16 (K=32).
//   D[n][m] = sum_k W[n][k] h[m][k]; C/D: col=l&15, row=4*(l>>4)+r.
// k-relabeling f(q,tg,e) = 32q+8tg+e on BOTH operands (bijection -> D
// unchanged): A-frag q = 8 contiguous W[n][32q+8tg..+7], B-frag q =
// h[32q+8tg..+7] from identity-layout LDS.  Wave w owns hidden
// [16w,16w+16); h exchanged via dbuf XOR-swizzled Hh, 1 barrier/step.
// x-projection = 3rd MFMA (q2): A=[Wa,Wb,bias]*gsc (tg0), B=[xa,xb,1]f16.
//
// R8/R9: f16 scheme: 16 gate-MFMAs/step, absmax floor 2.4e-4.
// R10-R12: occupancy hunt.  Allocator clamp = 2x-unified split:
//   (256,2)->108, (256,3)->84, (256,4)->64 arch VGPRs; spills are
//   catastrophic (R10: 1.5GB scratch).
// R13: W frags + x-proj evicted to LDS/MFMA: spills GONE (FETCH 11MB),
//   VGPR 68, but LDS 52KB and (256,3) both cap 3 blocks/CU.  Window
//   1470cy/wave-step: VALU 1029 (70%), MFMA 368 (25%), LDS ~26% ->
//   30% VALU idle = dependency stalls at 3 streams.  Floor ~350us.
// R14 (this round): 4th stream.  ONE batch tile/block (16 batch),
//   (256,4): VALU/wave-step halves (~530cy), wave-steps double, floor
//   unchanged -- but 4 indep blocks/SIMD fill the idle.  Fit:
//   LDS 39.5KB (WL 8 slots 32KB + Hh[2][16][64] 4KB + Xs16 1.3KB +
//   dbsL[256]f32 1KB (frees 16 regs, broadcast read) + LAc[2][64]f16
//   256B (b128 read per q, w0 only; m>=2 lanes read row m&1 -> D rows
//   2-15 garbage-but-finite, never read)).  VGPR naive ~60 <= 64 clamp
//   (allocator has beaten naive by ~14 each round).  Pass/fail:
//   VGPR<=64 AND FETCH stays ~11-25MB.  Predict occ 33->44, VALU
//   70->85+, rocprof 490->400-430.

#define LOG2E 1.44269504088896340736f
#define TWO_LOG2E 2.88539008177792681472f

typedef __attribute__((ext_vector_type(4))) short short4v;
typedef __attribute__((ext_vector_type(4))) float float4v;
typedef __attribute__((ext_vector_type(4))) unsigned int uint4v;
typedef _Float16 __attribute__((ext_vector_type(8))) half8v;

#if defined(__HIP_DEVICE_COMPILE__)
#define MFMAH(a, b, c) __builtin_amdgcn_mfma_f32_16x16x32_f16((a), (b), (c), 0, 0, 0)
#else
#define MFMAH(a, b, c) (c)
#endif

__device__ __forceinline__ float4v exp2v4(float4v x) {
  float4v r;
  r[0] = __builtin_amdgcn_exp2f(x[0]);
  r[1] = __builtin_amdgcn_exp2f(x[1]);
  r[2] = __builtin_amdgcn_exp2f(x[2]);
  r[3] = __builtin_amdgcn_exp2f(x[3]);
  return r;
}
__device__ __forceinline__ float4v rcpv4(float4v x) {
  float4v r;
  r[0] = __builtin_amdgcn_rcpf(x[0]);
  r[1] = __builtin_amdgcn_rcpf(x[1]);
  r[2] = __builtin_amdgcn_rcpf(x[2]);
  r[3] = __builtin_amdgcn_rcpf(x[3]);
  return r;
}

// Fused LSTM cell update on 4 rows (pk-f32).  a[0..3] = gates i,f,g,o
// PRE-SCALED (i,f,o by -log2e; g by 2log2e).  c holds 2log2e*cell.
__device__ __forceinline__ void cellact(const float4v* a, float4v& c,
                                        short4v& hh) {
  const float4v one = {1.f, 1.f, 1.f, 1.f};
  const float4v clo = {-36.f, -36.f, -36.f, -36.f};
  const float4v chi = {36.f, 36.f, 36.f, 36.f};
  float4v Ei = exp2v4(a[0]);                    // e^{-i}
  float4v Ef = exp2v4(a[1]);                    // e^{-f}
  float4v Eg = exp2v4(a[2]);                    // e^{2g}
  float4v Eo = exp2v4(a[3]);                    // e^{-o}
  float4v t1 = one + Ei;
  float4v t2 = one + Eg;
  float4v t3 = one + Ef;
  float4v t4s = Eg * TWO_LOG2E - TWO_LOG2E;     // 2log2e*(Eg-1)
  float4v P = t1 * t2;
  float4v num = c * P + t4s * t3;
  float4v cs = num * rcpv4(P * t3);             // 2log2e * c_new
  c = cs;
  float4v cl = __builtin_elementwise_min(__builtin_elementwise_max(cs, clo), chi);
  float4v Ec = exp2v4(cl);
  float4v h = (Ec - one) * rcpv4((one + Ec) * (one + Eo));
#pragma unroll
  for (int r = 0; r < 4; ++r) {
    _Float16 hf = (_Float16)h[r];               // v_cvt_f16_f32 (RNE)
    hh[r] = (short)__builtin_bit_cast(unsigned short, hf);
  }
}

__global__ __launch_bounds__(256, 4) void lstm_fused(
    const float* __restrict__ x,     // [B][20][2]
    const float* __restrict__ eWih,  // [256][2]
    const float* __restrict__ eWhh,  // [256][64]
    const float* __restrict__ ebih,  // [256]
    const float* __restrict__ ebhh,  // [256]
    const float* __restrict__ dWih,  // [256][64]
    const float* __restrict__ dWhh,  // [256][64]
    const float* __restrict__ dbih,  // [256]
    const float* __restrict__ dbhh,  // [256]
    const float* __restrict__ linW,  // [2][64]
    const float* __restrict__ linb,  // [2]
    float* __restrict__ out,         // [B][30][2]
    int B) {
  const int tid = threadIdx.x;
  const int w   = tid >> 6;    // wave: hidden block [16w, 16w+16)
  const int l   = tid & 63;
  const int m   = l & 15;      // batch col within tile
  const int tg  = l >> 4;
  const int msk = m & 14;
  const int wslot = (((w << 2) | tg) ^ msk) << 2;   // halfword off, b64 write
  const int bg  = blockIdx.x * 16;

  __shared__ __align__(16) unsigned short WL[8][256][8];  // W frags, f16
  __shared__ __align__(16) unsigned short Hh[2][16][64];  // h, f16 bits
  __shared__ unsigned int Xs16[16][21];                   // packed f16 x
  __shared__ __align__(16) float dbsL[256];               // dec bias, scaled
  __shared__ __align__(16) unsigned short LAc[2][64];     // linW f16 compact

  const half8v hz8 = {0, 0, 0, 0, 0, 0, 0, 0};
  const float4v zf = {0.f, 0.f, 0.f, 0.f};

  // ---- stage x as packed f16 pairs: Xs16[mm][st] = (xb|xa) ----
  {
    const size_t xoff = (size_t)blockIdx.x * 640;
    for (int i = tid; i < 320; i += 256) {
      int mm = i / 20, st = i - mm * 20;
      size_t g = xoff + (size_t)mm * 40 + st * 2;
      float xa = 0.f, xb = 0.f;
      if (g + 1 < (size_t)B * 40) { xa = x[g]; xb = x[g + 1]; }
      unsigned ua = __builtin_bit_cast(unsigned short, (_Float16)xa);
      unsigned ub = __builtin_bit_cast(unsigned short, (_Float16)xb);
      Xs16[mm][st] = (ub << 16) | ua;
    }
  }

  // ---- encoder weights: Whh frags -> WL[0..7]; x/bias frag q2 in regs ----
  half8v eA2[4];
#pragma unroll
  for (int gi = 0; gi < 4; ++gi) {
    const float gsc = (gi == 2) ? TWO_LOG2E : -LOG2E;
    const int nA = m + 16 * (4 * gi + w);
#pragma unroll
    for (int q = 0; q < 2; ++q) {
      const float* wp = &eWhh[nA * 64 + 32 * q + 8 * tg];
      float4v w0 = *(const float4v*)wp;
      float4v w1 = *(const float4v*)(wp + 4);
      half8v hi;
#pragma unroll
      for (int e = 0; e < 4; ++e) {
        hi[e]     = (_Float16)(w0[e] * gsc);
        hi[4 + e] = (_Float16)(w1[e] * gsc);
      }
      *(half8v*)&WL[gi * 2 + q][tid][0] = hi;
    }
    half8v a2 = hz8;
    if (tg == 0) {
      a2[0] = (_Float16)(eWih[nA * 2 + 0] * gsc);
      a2[1] = (_Float16)(eWih[nA * 2 + 1] * gsc);
      a2[2] = (_Float16)((ebih[nA] + ebhh[nA]) * gsc);
    }
    eA2[gi] = a2;
  }

  __syncthreads();   // Xs16 + WL ready

  float4v c0 = {0.f, 0.f, 0.f, 0.f};
  half8v b0[2] = {hz8, hz8};
  int p = 0;

  // ---- encoder: 20 steps ----
#pragma unroll 1
  for (int st = 0; st < 20; ++st) {
    uint4v t; t[0] = Xs16[m][st]; t[1] = 0x3C00u; t[2] = 0u; t[3] = 0u;
    half8v bq2 = __builtin_bit_cast(half8v, t);  // tg>0 lanes: eA2=0 anyway
    float4v a0[4];
#pragma unroll
    for (int gi = 0; gi < 4; ++gi) {
      half8v f0 = *(const half8v*)&WL[gi * 2 + 0][tid][0];
      half8v f1 = *(const half8v*)&WL[gi * 2 + 1][tid][0];
      float4v a = MFMAH(eA2[gi], bq2, zf);
      a = MFMAH(f0, b0[0], a);
      a0[gi] = MFMAH(f1, b0[1], a);
    }
    short4v hh0;
    cellact(a0, c0, hh0);
    *(short4v*)&Hh[p][m][wslot] = hh0;
    __syncthreads();
#pragma unroll
    for (int q = 0; q < 2; ++q) {
      const int rs = (((8 * q) | (2 * tg)) ^ msk) << 2;
      b0[q] = *(const half8v*)&Hh[p][m][rs];
    }
    p ^= 1;
  }

  // ---- transition: repack WL with decoder Wsum; dbs/LA -> compact LDS ----
  // (legal: every encoder WL read precedes the step-19 barrier)
#pragma unroll
  for (int gi = 0; gi < 4; ++gi) {
    const float gsc = (gi == 2) ? TWO_LOG2E : -LOG2E;
    const int nA = m + 16 * (4 * gi + w);
#pragma unroll
    for (int q = 0; q < 2; ++q) {
      const float* wpa = &dWih[nA * 64 + 32 * q + 8 * tg];
      const float* wpb = &dWhh[nA * 64 + 32 * q + 8 * tg];
      float4v a0v = *(const float4v*)wpa;
      float4v a1v = *(const float4v*)(wpa + 4);
      float4v b0v = *(const float4v*)wpb;
      float4v b1v = *(const float4v*)(wpb + 4);
      half8v hi;
#pragma unroll
      for (int e = 0; e < 4; ++e) {
        hi[e]     = (_Float16)((a0v[e] + b0v[e]) * gsc);
        hi[4 + e] = (_Float16)((a1v[e] + b1v[e]) * gsc);
      }
      *(half8v*)&WL[gi * 2 + q][tid][0] = hi;
    }
  }
  dbsL[tid] = (dbih[tid] + dbhh[tid]) * (((tid >> 6) == 2) ? TWO_LOG2E : -LOG2E);
  if (tid < 128) {
    LAc[tid >> 6][tid & 63] =
        __builtin_bit_cast(unsigned short, (_Float16)linW[tid]);
  }
  float4v lbinit = {0.f, 0.f, 0.f, 0.f};
  if (tg == 0) { lbinit[0] = linb[0]; lbinit[1] = linb[1]; }
  __syncthreads();   // decoder WL/dbsL/LAc ready

  // ---- decoder: 30 steps; out[st] emitted via MFMA after the exchange ----
#pragma unroll 1
  for (int st = 0; st < 30; ++st) {
    float4v a0[4];
#pragma unroll
    for (int gi = 0; gi < 4; ++gi) {
      half8v f0 = *(const half8v*)&WL[gi * 2 + 0][tid][0];
      half8v f1 = *(const half8v*)&WL[gi * 2 + 1][tid][0];
      float4v ci = *(const float4v*)&dbsL[64 * gi + 16 * w + 4 * tg];
      float4v a = MFMAH(f0, b0[0], ci);
      a0[gi] = MFMAH(f1, b0[1], a);
    }
    short4v hh0;
    cellact(a0, c0, hh0);
    *(short4v*)&Hh[p][m][wslot] = hh0;
    __syncthreads();
#pragma unroll
    for (int q = 0; q < 2; ++q) {
      const int rs = (((8 * q) | (2 * tg)) ^ msk) << 2;
      b0[q] = *(const half8v*)&Hh[p][m][rs];
    }
    // b-frags now hold h_st -> emit out[st] on the matrix pipe (wave 0).
    if (w == 0) {
      float4v la = lbinit;
#pragma unroll
      for (int q = 0; q < 2; ++q) {
        // m>=2 lanes read row m&1: D rows 2-15 garbage-but-finite, unread.
        half8v LAq = *(const half8v*)&LAc[m & 1][32 * q + 8 * tg];
        la = MFMAH(LAq, b0[q], la);
      }
      if (l < 16 && (bg + l) < B) {
        size_t oidx = ((size_t)(bg + l) * 30 + st) * 2;
        *(float2*)&out[oidx] = make_float2(la[0], la[1]);
      }
    }
    p ^= 1;
  }
}

extern "C" void kernel_launch(void* const* d_in, const int* in_sizes, int n_in,
                              void* d_out, int out_size, void* d_ws, size_t ws_size,
                              hipStream_t stream) {
  (void)n_in; (void)out_size; (void)d_ws; (void)ws_size;
  const float* x    = (const float*)d_in[0];
  const float* eWih = (const float*)d_in[1];
  const float* eWhh = (const float*)d_in[2];
  const float* ebih = (const float*)d_in[3];
  const float* ebhh = (const float*)d_in[4];
  const float* dWih = (const float*)d_in[5];
  const float* dWhh = (const float*)d_in[6];
  const float* dbih = (const float*)d_in[7];
  const float* dbhh = (const float*)d_in[8];
  const float* linW = (const float*)d_in[9];
  const float* linb = (const float*)d_in[10];

  const int B = in_sizes[0] / 40;          // [B][20][2]
  const int grid = (B + 15) / 16;          // 16 batch elems per block (1 tile)
  lstm_fused<<<grid, 256, 0, stream>>>(x, eWih, eWhh, ebih, ebhh,
                                       dWih, dWhh, dbih, dbhh, linW, linb,
                                       (float*)d_out, B);
}